// Round 8
// baseline (1250.106 us; speedup 1.0000x reference)
//
#include <hip/hip_runtime.h>
#include <math.h>
#include <stdint.h>

typedef unsigned short u16;
typedef float f32x4 __attribute__((ext_vector_type(4)));
typedef short bf16x8 __attribute__((ext_vector_type(8)));

#define NVIEW 6

// ---------- helpers ----------
__device__ __forceinline__ u16 f2bf(float f){
  unsigned u = __float_as_uint(f);
  u += 0x7FFFu + ((u >> 16) & 1u);      // round-to-nearest-even
  return (u16)(u >> 16);
}
__device__ __forceinline__ float bf2f(u16 h){
  return __uint_as_float(((unsigned)h) << 16);
}
__device__ __forceinline__ float fsig(float x){
  x = fminf(fmaxf(x, -30.f), 30.f);
  return 1.0f / (1.0f + __expf(-x));
}
__device__ __forceinline__ float ftanh(float x){
  x = fminf(fmaxf(x, -15.f), 15.f);
  float e = __expf(2.0f * x);
  return (e - 1.0f) / (e + 1.0f);
}
// exact GELU via Abramowitz-Stegun 7.1.26 erf (|err| < 1.5e-7, way under bf16 ulp)
__device__ __forceinline__ float gelu_exact(float v){
  float x  = v * 0.70710678118654752f;
  float ax = fabsf(x);
  float t  = 1.0f / fmaf(0.3275911f, ax, 1.0f);
  float p  = t * fmaf(t, fmaf(t, fmaf(t, fmaf(t, 1.061405429f, -1.453152027f),
                                      1.421413741f), -0.284496736f), 0.254829592f);
  float er = copysignf(1.0f - p * __expf(-ax * ax), x);
  return 0.5f * v * (1.0f + er);
}
__device__ __forceinline__ void gload16(const u16* g, u16* l){
  __builtin_amdgcn_global_load_lds((const __attribute__((address_space(1))) unsigned int*)g,
                                   (__attribute__((address_space(3))) unsigned int*)l,
                                   16, 0, 0);
}

// ---------- setup kernels ----------
__global__ void k_cvt(const float* __restrict__ in, u16* __restrict__ out, long n4){
  long i = (long)blockIdx.x * blockDim.x + threadIdx.x;
  long stride = (long)gridDim.x * blockDim.x;
  for (; i < n4; i += stride){
    const float4 v = ((const float4*)in)[i];
    ushort4 o;
    o.x = f2bf(v.x); o.y = f2bf(v.y); o.z = f2bf(v.z); o.w = f2bf(v.w);
    ((ushort4*)out)[i] = o;
  }
}

// Wl[l][4u+q][k] = (k<256 ? Wih[l][q*256+u][k] : Whh[l][q*256+u][k-256]) as bf16
__global__ void k_build_wl(const float* __restrict__ Wih, const float* __restrict__ Whh,
                           u16* __restrict__ Wl){
  int idx = blockIdx.x * 256 + threadIdx.x;   // exactly 3*1024*512 threads
  int l   = idx >> 19;
  int rem = idx & 524287;
  int ro  = rem >> 9;       // interleaved out-row 0..1023
  int k   = rem & 511;
  int u = ro >> 2, q = ro & 3;
  int ri = q * 256 + u;
  float v = (k < 256) ? Wih[(l * 1024 + ri) * 256 + k]
                      : Whh[(l * 1024 + ri) * 256 + (k - 256)];
  Wl[idx] = f2bf(v);
}

__global__ void k_build_bias(const float* __restrict__ bih, const float* __restrict__ bhh,
                             float* __restrict__ biasL, u16* __restrict__ zbuf){
  int idx = blockIdx.x * 256 + threadIdx.x;
  if (idx < 3072){
    int l = idx >> 10; int ro = idx & 1023;
    int u = ro >> 2, q = ro & 3;
    int ri = q * 256 + u;
    biasL[idx] = bih[l * 1024 + ri] + bhh[l * 1024 + ri];
  }
  if (idx < 256) zbuf[idx] = 0;
}

// =====================================================================
// Big-wave-tile deep-ring GEMM: C[m,n] = sum_k A[m,k]*B[n,k] (B [N][K] bf16)
// Block 256 x (32*NF); 256 threads = 4 waves (2M x 2N), wave tile
// 128 x (16*NF), BK = 32.  NF=8: 16 ds_reads feed 64 MFMAs (0.25/MFMA).
// LDS ring: 4 slots of (A 16 KB + B 2*NF KB); NF=8 -> 128 KB (1 blk/CU),
// NF=4 -> 96 KB.  Prefetch 3 tiles deep; steady wait vmcnt(2*LPS) so a
// wave only waits on loads issued ~3 tiles (~3000 cyc) earlier; one
// drain-free raw s_barrier per tile (per-wave vmcnt before it).
// LDS swizzle (row-pair 8-slot XOR, verified r7: conflicts -> 0):
//   rp=row>>1 (128 B = 8 slots of 16 B); s_log=(row&1)*4+c16;
//   s_phys = s_log ^ (rp&7).  Staged via inverse perm on the GLOBAL
//   source + linear LDS dest (rule 21); read XOR is a per-lane constant.
// Grid: 1-D, XCD-chunked bijective swizzle, n-fastest decode.
// A split in K: cols [0,K0) from A0 (stride sA0), rest from A1 (sA1).
// EPI 0: out = bf16(gelu_exact(acc+bias[n]) + resid[m*N+n])
// EPI 1: out = bf16(acc+bias[n])
// EPI 2: fused LSTM cell (gate-interleaved N=1024), h->outb, c<->cbuf.
// =====================================================================
template<int EPI, int NF>
__global__ __launch_bounds__(256, 1)
void gemm_big(const u16* __restrict__ A0, long sA0,
              const u16* __restrict__ A1, long sA1, int K0,
              const u16* __restrict__ Bm, long sB,
              int N, int K, int NBn,
              const float* __restrict__ bias,
              const float* __restrict__ resid,
              u16* __restrict__ outb,
              float* __restrict__ cbuf,
              int tstep)
{
  constexpr int SLOT_A = 8192;          // u16 per A slot (256 rows x 32)
  constexpr int SLOT_B = 1024 * NF;     // u16 per B slot (32*NF rows x 32)
  constexpr int BCH    = NF / 2;        // 64-row chunks in B tile
  __shared__ __align__(16) u16 lA[4 * SLOT_A];
  __shared__ __align__(16) u16 lB[4 * SLOT_B];

  const int tid  = threadIdx.x;
  const int lane = tid & 63;
  const int wid  = tid >> 6;
  const int wm = wid >> 1, wn = wid & 1;
  const int l15 = lane & 15, lk = lane >> 4;

  // XCD-chunked bijective swizzle (grids are multiples of 8), n fastest
  const int nwg = gridDim.x;
  const int qx  = nwg >> 3;
  const int bb  = blockIdx.x;
  const int swz = (bb & 7) * qx + (bb >> 3);
  const long m0 = (long)(swz / NBn) * 256;
  const int  n0 = (swz % NBn) * (32 * NF);
  const int  NT = K >> 5;

  // ---- staging mapping (inverse swizzle on global source) ----
  const int rA0 = tid >> 2;             // 0..63 (row within 64-row chunk)
  const int cA  = tid & 3;              // physical c16 within row
  const int slog = (((rA0 & 1) << 2) | cA) ^ ((rA0 >> 1) & 7);
  const int srow = (rA0 & ~1) | (slog >> 2);     // source row in chunk
  const int scol = (slog & 3) << 3;              // source col (elements)
  const int ldst = rA0 * 32 + cA * 8;            // linear LDS dest (u16)

  auto STAGE = [&](int slot, int t){
    const int kb = t << 5;
    #pragma unroll
    for (int c = 0; c < 4; ++c){
      const int r  = c * 64 + srow;
      const int gc = kb + scol;
      const u16* s = (EPI == 2 && gc >= K0) ? (A1 + (m0 + r) * sA1 + (gc - K0))
                                            : (A0 + (m0 + r) * sA0 + gc);
      gload16(s, &lA[slot * SLOT_A + c * 2048 + ldst]);
    }
    #pragma unroll
    for (int c = 0; c < BCH; ++c){
      const int r = c * 64 + srow;
      gload16(Bm + (long)(n0 + r) * sB + (kb + scol),
              &lB[slot * SLOT_B + c * 2048 + ldst]);
    }
  };

  f32x4 acc[8][NF];
  #pragma unroll
  for (int i = 0; i < 8; ++i)
    #pragma unroll
    for (int j = 0; j < NF; ++j)
      acc[i][j] = (f32x4){0.f, 0.f, 0.f, 0.f};

  // ---- swizzled read offsets (u16 units): rp*64 + s_phys*8 ----
  const int spA = (((l15 & 1) << 2) | lk) ^ (l15 >> 1);   // per-lane constant
  const int rdA = (wm * 64 + (l15 >> 1)) * 64 + spA * 8;          // 128-row half
  const int rdB = (wn * 8 * NF + (l15 >> 1)) * 64 + spA * 8;      // 16*NF-row half

  auto COMPUTE = [&](int slot){
    bf16x8 af[8], bq[NF];
    #pragma unroll
    for (int mf = 0; mf < 8; ++mf)
      af[mf] = *(const bf16x8*)&lA[slot * SLOT_A + rdA + mf * 512];
    #pragma unroll
    for (int nf = 0; nf < NF; ++nf)
      bq[nf] = *(const bf16x8*)&lB[slot * SLOT_B + rdB + nf * 512];
    #pragma unroll
    for (int mf = 0; mf < 8; ++mf)
      #pragma unroll
      for (int nf = 0; nf < NF; ++nf)
        acc[mf][nf] = __builtin_amdgcn_mfma_f32_16x16x32_bf16(af[mf], bq[nf], acc[mf][nf], 0, 0, 0);
  };

  // waits: LPS = 4 + NF/2 loads per STAGE; steady = 2 stages in flight
#define WAIT2 do{ if constexpr (NF == 8) asm volatile("s_waitcnt vmcnt(16)" ::: "memory"); \
                  else                   asm volatile("s_waitcnt vmcnt(12)" ::: "memory"); }while(0)
#define WAIT1 do{ if constexpr (NF == 8) asm volatile("s_waitcnt vmcnt(8)" ::: "memory");  \
                  else                   asm volatile("s_waitcnt vmcnt(6)" ::: "memory"); }while(0)
#define WAIT0 asm volatile("s_waitcnt vmcnt(0)" ::: "memory")
#define BARR  asm volatile("s_barrier" ::: "memory")

  // prologue: fill 3 ring slots
  STAGE(0, 0); STAGE(1, 1); STAGE(2, 2);

  for (int t = 0; t < NT - 3; ++t){
    WAIT2; BARR;
    STAGE((t + 3) & 3, t + 3);
    COMPUTE(t & 3);
  }
  WAIT2; BARR; COMPUTE((NT - 3) & 3);
  WAIT1; BARR; COMPUTE((NT - 2) & 3);
  WAIT0; BARR; COMPUTE((NT - 1) & 3);

#undef WAIT2
#undef WAIT1
#undef WAIT0
#undef BARR

  // ---- epilogue ----
  if (EPI == 0 || EPI == 1){
    #pragma unroll
    for (int mf = 0; mf < 8; ++mf){
      #pragma unroll
      for (int nf = 0; nf < NF; ++nf){
        int  n    = n0 + wn * (16 * NF) + nf * 16 + l15;
        long mrow = m0 + wm * 128 + mf * 16 + lk * 4;
        float bz = bias[n];
        #pragma unroll
        for (int r = 0; r < 4; ++r){
          float v = acc[mf][nf][r] + bz;
          long off = (mrow + r) * N + n;
          if (EPI == 0) v = gelu_exact(v) + resid[off];
          outb[off] = f2bf(v);
        }
      }
    }
  } else {
    // LSTM cell epilogue. D-frag: row=(lane>>4)*4+reg, col=lane&15.
    // Quad lanes hold gates i,f,g,o of unit u=n>>2; 4x4 quad transpose.
    const int a  = lane & 3;
    const int qb = lane & ~3;
    #pragma unroll
    for (int mf = 0; mf < 8; ++mf){
      #pragma unroll
      for (int nf = 0; nf < NF; ++nf){
        int n = n0 + wn * (16 * NF) + nf * 16 + l15;
        float bz = bias[n];
        float v0 = acc[mf][nf][0] + bz;
        float v1 = acc[mf][nf][1] + bz;
        float v2 = acc[mf][nf][2] + bz;
        float v3 = acc[mf][nf][3] + bz;
        float s0 = (a == 0) ? v0 : (a == 1) ? v1 : (a == 2) ? v2 : v3;
        float s1 = (a == 0) ? v1 : (a == 1) ? v2 : (a == 2) ? v3 : v0;
        float s2 = (a == 0) ? v2 : (a == 1) ? v3 : (a == 2) ? v0 : v1;
        float s3 = (a == 0) ? v3 : (a == 1) ? v0 : (a == 2) ? v1 : v2;
        float r0 = s0;
        float r1 = __shfl(s1, qb + ((a + 3) & 3));
        float r2 = __shfl(s2, qb + ((a + 2) & 3));
        float r3 = __shfl(s3, qb + ((a + 1) & 3));
        float wi = (a == 0) ? r0 : (a == 1) ? r1 : (a == 2) ? r2 : r3;
        float wf = (a == 1) ? r0 : (a == 2) ? r1 : (a == 3) ? r2 : r3;
        float wg = (a == 2) ? r0 : (a == 3) ? r1 : (a == 0) ? r2 : r3;
        float wo = (a == 3) ? r0 : (a == 0) ? r1 : (a == 1) ? r2 : r3;
        long row = m0 + wm * 128 + mf * 16 + lk * 4 + a;
        int  u   = ((n0 + wn * (16 * NF) + nf * 16) >> 2) + (l15 >> 2);
        float c_old = (tstep == 0) ? 0.0f : cbuf[row * 256 + u];
        float ii = fsig(wi), ff = fsig(wf), gg = ftanh(wg), oo = fsig(wo);
        float cn = ff * c_old + ii * gg;
        float hn = oo * ftanh(cn);
        cbuf[row * 256 + u] = cn;
        outb[(row * NVIEW + tstep) * 256 + u] = f2bf(hn);
      }
    }
  }
}

// ---------- tail: viewport + score + mean ----------
__global__ void k_score(const u16* __restrict__ X3, const float* __restrict__ Wv,
                        const float* __restrict__ bv, const float* __restrict__ Ws,
                        const float* __restrict__ bs, float* __restrict__ score){
  int lane = threadIdx.x & 63;
  int bm = blockIdx.x * 4 + (threadIdx.x >> 6);
  const u16* row = X3 + (long)bm * (NVIEW * 256);
  float4 wv = *(const float4*)(Wv + lane * 4);
  float p = 0.f;
  #pragma unroll
  for (int n = 0; n < NVIEW; ++n){
    ushort4 xv = *(const ushort4*)(row + n * 256 + lane * 4);
    float d = bf2f(xv.x) * wv.x + bf2f(xv.y) * wv.y + bf2f(xv.z) * wv.z + bf2f(xv.w) * wv.w;
    p += Ws[n] * d;
  }
  #pragma unroll
  for (int off = 32; off; off >>= 1) p += __shfl_xor(p, off);
  if (lane == 0){
    float sw = Ws[0] + Ws[1] + Ws[2] + Ws[3] + Ws[4] + Ws[5];
    score[bm] = p + bv[0] * sw + bs[0];
  }
}

__global__ void k_mean(const float* __restrict__ score, float* __restrict__ out){
  __shared__ float red[256];
  int b = blockIdx.x, tid = threadIdx.x;
  red[tid] = score[b * 256 + tid];
  __syncthreads();
  for (int s = 128; s > 0; s >>= 1){
    if (tid < s) red[tid] += red[tid + s];
    __syncthreads();
  }
  if (tid == 0) out[b] = red[0] * (1.0f / 256.0f);
}

// ---------- launcher ----------
extern "C" void kernel_launch(void* const* d_in, const int* in_sizes, int n_in,
                              void* d_out, int out_size, void* d_ws, size_t ws_size,
                              hipStream_t stream){
  const float* swin = (const float*)d_in[0];
  const float* conv = (const float*)d_in[1];
  const float* Wc   = (const float*)d_in[2];
  const float* bc   = (const float*)d_in[3];
  const float* Win  = (const float*)d_in[4];
  const float* b_in = (const float*)d_in[5];
  const float* Wih  = (const float*)d_in[6];
  const float* Whh  = (const float*)d_in[7];
  const float* bih  = (const float*)d_in[8];
  const float* bhh  = (const float*)d_in[9];
  const float* Wv   = (const float*)d_in[10];
  const float* bv   = (const float*)d_in[11];
  const float* Ws   = (const float*)d_in[12];
  const float* bs   = (const float*)d_in[13];
  float* out = (float*)d_out;

  // workspace layout (~207 MB total)
  char* w = (char*)d_ws;
  u16*  convb = (u16*)(w);                    // 100,663,296 B  [49152*1024] bf16
  u16*  X0    = (u16*)(w);                    // reuses convb region after G1
  u16*  XA    = (u16*)(w + 25165824);
  u16*  XB    = (u16*)(w + 50331648);
  float* cbuf = (float*)(w + 75497472);
  u16*  Y     = (u16*)(w + 100663296);        // 100,663,296  (plain [49152][1024])
  u16*  Wcb   = (u16*)(w + 201326592);
  u16*  Winb  = (u16*)(w + 203423744);
  u16*  Wl    = (u16*)(w + 203948032);
  float* biasL= (float*)(w + 207093760);
  u16*  zbuf  = (u16*)(w + 207106048);
  float* scoreb = (float*)(w + 207106560);

  // 1) converts + weight transforms
  k_cvt<<<4096, 256, 0, stream>>>(conv, convb, 49152L * 1024 / 4);
  k_cvt<<<512, 256, 0, stream>>>(Wc, Wcb, 1048576 / 4);
  k_cvt<<<128, 256, 0, stream>>>(Win, Winb, 262144 / 4);
  k_build_wl<<<6144, 256, 0, stream>>>(Wih, Whh, Wl);
  k_build_bias<<<12, 256, 0, stream>>>(bih, bhh, biasL, zbuf);

  // 2) G1: Y = bf16( gelu(conv @ Wc^T + bc) + swin )   [49152 x 1024], NBn=4
  gemm_big<0, 8><<<768, 256, 0, stream>>>(
      convb, 1024L, convb, 1024L, 1024,
      Wcb, 1024L, 1024, 1024, 4, bc, swin, Y, (float*)nullptr, 0);

  // 3) G2: X0 = bf16( Y @ Win^T + b_in )               [49152 x 256], NBn=1
  gemm_big<1, 8><<<192, 256, 0, stream>>>(
      Y, 1024L, Y, 1024L, 1024,
      Winb, 1024L, 256, 1024, 1, b_in, (const float*)nullptr, X0, (float*)nullptr, 0);

  // 4) LSTM: 3 layers x 6 timesteps; gates = [x_t, h_{t-1}] @ Wl^T + bias (K=512)
  const u16* xin = X0;
  u16* xout = XA;
  for (int l = 0; l < 3; ++l){
    for (int t = 0; t < 6; ++t){
      const u16* a1 = (t == 0) ? zbuf : (xout + (t - 1) * 256);
      long s1 = (t == 0) ? 0L : 1536L;
      gemm_big<2, 4><<<256, 256, 0, stream>>>(
          xin + t * 256, 1536L, a1, s1, 256,
          Wl + l * 1024 * 512, 512L, 1024, 512, 8,
          biasL + l * 1024, (const float*)nullptr,
          xout, cbuf, t);
    }
    if (l == 0){ xin = XA; xout = XB; }
    else if (l == 1){ xin = XB; xout = XA; }
  }

  // 5) viewport + score + mean
  k_score<<<2048, 256, 0, stream>>>(XA, Wv, bv, Ws, bs, scoreb);
  k_mean<<<32, 256, 0, stream>>>(scoreb, out);
}

// Round 9
// 812.695 us; speedup vs baseline: 1.5382x; 1.5382x over previous
//
#include <hip/hip_runtime.h>
#include <math.h>
#include <stdint.h>

typedef unsigned short u16;
typedef float f32x4 __attribute__((ext_vector_type(4)));
typedef short bf16x8 __attribute__((ext_vector_type(8)));

#define NVIEW 6

// ---------- helpers ----------
__device__ __forceinline__ u16 f2bf(float f){
  unsigned u = __float_as_uint(f);
  u += 0x7FFFu + ((u >> 16) & 1u);
  return (u16)(u >> 16);
}
__device__ __forceinline__ float bf2f(u16 h){
  return __uint_as_float(((unsigned)h) << 16);
}
__device__ __forceinline__ float fsig(float x){
  x = fminf(fmaxf(x, -30.f), 30.f);
  return 1.0f / (1.0f + __expf(-x));
}
__device__ __forceinline__ float ftanh(float x){
  x = fminf(fmaxf(x, -15.f), 15.f);
  float e = __expf(2.0f * x);
  return (e - 1.0f) / (e + 1.0f);
}
__device__ __forceinline__ float gelu_exact(float v){
  float x  = v * 0.70710678118654752f;
  float ax = fabsf(x);
  float t  = 1.0f / fmaf(0.3275911f, ax, 1.0f);
  float p  = t * fmaf(t, fmaf(t, fmaf(t, fmaf(t, 1.061405429f, -1.453152027f),
                                      1.421413741f), -0.284496736f), 0.254829592f);
  float er = copysignf(1.0f - p * __expf(-ax * ax), x);
  return 0.5f * v * (1.0f + er);
}
__device__ __forceinline__ void gload16(const u16* g, u16* l){
  __builtin_amdgcn_global_load_lds((const __attribute__((address_space(1))) unsigned int*)g,
                                   (__attribute__((address_space(3))) unsigned int*)l,
                                   16, 0, 0);
}

// ---------- setup kernels ----------
__global__ void k_cvt(const float* __restrict__ in, u16* __restrict__ out, long n4){
  long i = (long)blockIdx.x * blockDim.x + threadIdx.x;
  long stride = (long)gridDim.x * blockDim.x;
  for (; i < n4; i += stride){
    const float4 v = ((const float4*)in)[i];
    ushort4 o;
    o.x = f2bf(v.x); o.y = f2bf(v.y); o.z = f2bf(v.z); o.w = f2bf(v.w);
    ((ushort4*)out)[i] = o;
  }
}

__global__ void k_build_wl(const float* __restrict__ Wih, const float* __restrict__ Whh,
                           u16* __restrict__ Wl){
  int idx = blockIdx.x * 256 + threadIdx.x;
  int l   = idx >> 19;
  int rem = idx & 524287;
  int ro  = rem >> 9;
  int k   = rem & 511;
  int u = ro >> 2, q = ro & 3;
  int ri = q * 256 + u;
  float v = (k < 256) ? Wih[(l * 1024 + ri) * 256 + k]
                      : Whh[(l * 1024 + ri) * 256 + (k - 256)];
  Wl[idx] = f2bf(v);
}

__global__ void k_build_bias(const float* __restrict__ bih, const float* __restrict__ bhh,
                             float* __restrict__ biasL, u16* __restrict__ zbuf){
  int idx = blockIdx.x * 256 + threadIdx.x;
  if (idx < 3072){
    int l = idx >> 10; int ro = idx & 1023;
    int u = ro >> 2, q = ro & 3;
    int ri = q * 256 + u;
    biasL[idx] = bih[l * 1024 + ri] + bhh[l * 1024 + ri];
  }
  if (idx < 256) zbuf[idx] = 0;
}

// =====================================================================
// m201-faithful 8-phase 256x256 GEMM with READ-AHEAD fragment pipelining.
// 512 thr = 8 waves (2M x 4N), wave tile 128x64, BK=64, dbuf 128 KiB.
// Key mechanism (the r1-r3 ports missed it): each phase's 16 MFMAs use
// fragments ds_read during the PREVIOUS phase (ping-pong regs aF0/aF1,
// bF0/bF1) -> the post-barrier lgkmcnt(0) is nearly free; per-phase reads
// alternate 4 (A-group) / 8 (A+B).  Staging: one 16KB half-tile per phase
// (2 gload_lds/thread), slot order chosen so each half is overwritten only
// after its last ds_read; drains vmcnt(2) at ph3/ph7 (vmcnt(0) last iter).
// LDS swizzle: row r (128B) slots s: s_phys = s_log ^ (r&7), staged via
// inverse-permuted global source + linear dest (rule 21); read-side XOR is
// a per-lane constant; ks1 = ks0 addr ^ 64.
// =====================================================================
#define DSRI(dst, addr, imm) \
  asm volatile("ds_read_b128 %0, %1 offset:%2" : "=v"(dst) : "v"(addr), "i"(imm))

template<int EPI>
__global__ __launch_bounds__(512, 2)
void gemm8(const u16* __restrict__ A, long sA,
           const u16* __restrict__ Bm, long sB,
           int N, int K, int NBn,
           const float* __restrict__ bias,
           const float* __restrict__ resid,
           u16* __restrict__ outb)
{
  __shared__ __align__(128) u16 sh[65536];   // A: u16[0,32768)  B: [32768,65536)

  const int tid  = threadIdx.x;
  const int lane = tid & 63;
  const int wv   = tid >> 6;           // 0..7
  const int wm   = wv >> 2;            // 0..1
  const int wn   = wv & 3;             // 0..3
  const int l15  = lane & 15, lk = lane >> 4;
  const int w2   = wv * 2;

  const int nwg = gridDim.x;
  const int qx  = nwg >> 3;
  const int bb  = blockIdx.x;
  const int swz = (bb & 7) * qx + (bb >> 3);
  const long m0 = (long)(swz / NBn) * 256;
  const int  n0 = (swz % NBn) * 256;
  const int  NT  = K >> 6;
  const int  NIT = NT >> 1;

  // staging per-lane source perm: row += lane>>3, col = ((lane&7)^(lane>>3))*8
  const u16* aSrc = A  + (m0 + (lane >> 3)) * sA + (((lane & 7) ^ (lane >> 3)) << 3);
  const u16* bSrc = Bm + ((long)n0 + (lane >> 3)) * sB + (((lane & 7) ^ (lane >> 3)) << 3);

  auto STA8 = [&](int buf, int half, int t){
    const u16* s = aSrc + ((long)(half * 128 + w2 * 8)) * sA + ((long)t << 6);
    u16* d = &sh[buf * 16384 + half * 8192 + w2 * 512 + lane * 8];
    gload16(s, d);
    gload16(s + 8 * sA, d + 512);
  };
  auto STB8 = [&](int buf, int half, int t){
    const u16* s = bSrc + ((long)(half * 128 + w2 * 8)) * sB + ((long)t << 6);
    u16* d = &sh[32768 + buf * 16384 + half * 8192 + w2 * 512 + lane * 8];
    gload16(s, d);
    gload16(s + 8 * sB, d + 512);
  };

  // read addresses (bytes): row*128 + ((lk^(l15&7))<<4); ks1 = ks0 ^ 64
  const unsigned ldsBase = (unsigned)(uintptr_t)&sh[0];
  const unsigned spb = (unsigned)((lk ^ (l15 & 7)) << 4);
  const unsigned aRd0 = ldsBase + wm * 16384 + l15 * 128 + spb;
  const unsigned aRd1 = aRd0 ^ 64;
  const unsigned bRd0 = ldsBase + 65536 + (wn >> 1) * 16384 + ((wn & 1) * 64 + l15) * 128 + spb;
  const unsigned bRd1 = bRd0 ^ 64;

#define RDA(BUF, G, KS, DST) do{ const unsigned _a = (KS) ? aRd1 : aRd0;          \
    DSRI(DST[0], _a, (BUF)*32768 + (G)*8192 + 0);                                 \
    DSRI(DST[1], _a, (BUF)*32768 + (G)*8192 + 2048);                              \
    DSRI(DST[2], _a, (BUF)*32768 + (G)*8192 + 4096);                              \
    DSRI(DST[3], _a, (BUF)*32768 + (G)*8192 + 6144); }while(0)
#define RDB(BUF, KS, DST) do{ const unsigned _b = (KS) ? bRd1 : bRd0;             \
    DSRI(DST[0], _b, (BUF)*32768 + 0);                                            \
    DSRI(DST[1], _b, (BUF)*32768 + 2048);                                         \
    DSRI(DST[2], _b, (BUF)*32768 + 4096);                                         \
    DSRI(DST[3], _b, (BUF)*32768 + 6144); }while(0)

  f32x4 acc[8][4];
  #pragma unroll
  for (int i = 0; i < 8; ++i)
    #pragma unroll
    for (int j = 0; j < 4; ++j)
      acc[i][j] = (f32x4){0.f, 0.f, 0.f, 0.f};

  bf16x8 aF0[4], aF1[4], bF0[4], bF1[4];

  // ---- prologue: b0 full (tile0) + b1.B0,B1 (tile1); then read-ahead ----
  STA8(0, 0, 0); STA8(0, 1, 0); STB8(0, 0, 0); STB8(0, 1, 0);
  STB8(1, 0, 1); STB8(1, 1, 1);
  asm volatile("s_waitcnt vmcnt(4)" ::: "memory");   // b0 fully landed
  __builtin_amdgcn_s_barrier();
  RDA(0, 0, 0, aF0); RDB(0, 0, bF0);                  // ph1 operands

// one phase: reads(next) ; stage ; barrier ; lgkm0+fence ; 16 MFMA ; [vm] ; barrier
#define PH(G, AU, BU, RDS, STG, VM) {                                             \
    RDS;                                                                          \
    STG;                                                                          \
    __builtin_amdgcn_s_barrier();                                                 \
    asm volatile("s_waitcnt lgkmcnt(0)" ::: "memory");                            \
    __builtin_amdgcn_sched_barrier(0);                                            \
    __builtin_amdgcn_s_setprio(1);                                                \
    _Pragma("unroll") for (int i = 0; i < 4; ++i)                                 \
      _Pragma("unroll") for (int nf = 0; nf < 4; ++nf)                            \
        acc[(G)*4 + i][nf] = __builtin_amdgcn_mfma_f32_16x16x32_bf16(             \
            AU[i], BU[nf], acc[(G)*4 + i][nf], 0, 0, 0);                          \
    __builtin_amdgcn_s_setprio(0);                                                \
    VM;                                                                           \
    __builtin_amdgcn_s_barrier(); }

#define VM2C { if (nl) { asm volatile("s_waitcnt vmcnt(2)" ::: "memory"); }        \
               else    { asm volatile("s_waitcnt vmcnt(0)" ::: "memory"); } }
#define NOVM { }

  for (int I = 0; I < NIT; ++I){
    const int t1 = 2 * I + 1;
    const bool nl = (I < NIT - 1);
    // tile 2I in buf0 (ph1-4), tile 2I+1 in buf1 (ph5-8)
    PH(0, aF0, bF0, RDA(0,1,0,aF1),                 STA8(1,0,t1),               NOVM)  // ph1
    PH(1, aF1, bF0, { RDA(0,0,1,aF0); RDB(0,1,bF1);}, STA8(1,1,t1),             NOVM)  // ph2
    PH(0, aF0, bF1, RDA(0,1,1,aF1),                 if (nl) STB8(0,0,t1+1);,    VM2C)  // ph3
    PH(1, aF1, bF1, { RDA(1,0,0,aF0); RDB(1,0,bF0);}, if (nl) STB8(0,1,t1+1);, NOVM)  // ph4
    PH(0, aF0, bF0, RDA(1,1,0,aF1),                 if (nl) STA8(0,0,t1+1);,    NOVM)  // ph5
    PH(1, aF1, bF0, { RDA(1,0,1,aF0); RDB(1,1,bF1);}, if (nl) STA8(0,1,t1+1);, NOVM)  // ph6
    PH(0, aF0, bF1, RDA(1,1,1,aF1),                 if (nl) STB8(1,0,t1+2);,    VM2C)  // ph7
    PH(1, aF1, bF1, { RDA(0,0,0,aF0); RDB(0,0,bF0);}, if (nl) STB8(1,1,t1+2);, NOVM)  // ph8
  }
#undef PH
#undef VM2C
#undef NOVM
#undef RDA
#undef RDB

  // ---- epilogue ----
  #pragma unroll
  for (int mf = 0; mf < 8; ++mf){
    #pragma unroll
    for (int nf = 0; nf < 4; ++nf){
      const int n = n0 + wn * 64 + nf * 16 + l15;
      const float bz = bias[n];
      const long mrow = m0 + wm * 128 + mf * 16 + lk * 4;
      #pragma unroll
      for (int r = 0; r < 4; ++r){
        float v = acc[mf][nf][r] + bz;
        const long off = (mrow + r) * (long)N + n;
        if (EPI == 0) v = gelu_exact(v) + resid[off];
        outb[off] = f2bf(v);
      }
    }
  }
}

// ---------- deep-ring 128x128 GEMM (R7-proven) for G2 + LSTM ----------
template<int EPI>
__global__ __launch_bounds__(256, 2)
void gemm_dr(const u16* __restrict__ A0, long sA0,
             const u16* __restrict__ A1, long sA1, int K0,
             const u16* __restrict__ Bm, long sB,
             int N, int K, int NBn,
             const float* __restrict__ bias,
             const float* __restrict__ resid,
             u16* __restrict__ outb,
             float* __restrict__ cbuf,
             int tstep)
{
  __shared__ __align__(16) u16 lA[5 * 4096];
  __shared__ __align__(16) u16 lB[5 * 4096];

  const int tid  = threadIdx.x;
  const int lane = tid & 63;
  const int wid  = tid >> 6;
  const int wm = wid >> 1, wn = wid & 1;
  const int l15 = lane & 15, lk = lane >> 4;

  const int nwg = gridDim.x;
  const int qx  = nwg >> 3;
  const int bb  = blockIdx.x;
  const int swz = (bb & 7) * qx + (bb >> 3);
  const long m0 = (long)(swz / NBn) * 128;
  const int  n0 = (swz % NBn) * 128;
  const int  NT = K >> 5;

  const int rA0 = tid >> 2;
  const int cA  = tid & 3;
  const int slog = (((rA0 & 1) << 2) | cA) ^ ((rA0 >> 1) & 7);
  const int srow = (rA0 & ~1) | (slog >> 2);
  const int scol = (slog & 3) << 3;
  const int ldst = rA0 * 32 + cA * 8;

  auto STAGE = [&](int slot, int t){
    const int kb = t << 5;
    const int so = slot * 4096;
    #pragma unroll
    for (int c = 0; c < 2; ++c){
      const int r  = c * 64 + srow;
      const int gc = kb + scol;
      const u16* s = (gc < K0) ? (A0 + (m0 + r) * sA0 + gc)
                               : (A1 + (m0 + r) * sA1 + (gc - K0));
      gload16(s, &lA[so + c * 2048 + ldst]);
    }
    #pragma unroll
    for (int c = 0; c < 2; ++c){
      const int r  = c * 64 + srow;
      const int gc = kb + scol;
      gload16(Bm + (long)(n0 + r) * sB + gc, &lB[so + c * 2048 + ldst]);
    }
  };

  f32x4 acc[4][4];
  #pragma unroll
  for (int i = 0; i < 4; ++i)
    #pragma unroll
    for (int j = 0; j < 4; ++j)
      acc[i][j] = (f32x4){0.f, 0.f, 0.f, 0.f};

  const int spA = (((l15 & 1) << 2) | lk) ^ (l15 >> 1);
  const int rdA = (wm * 32 + (l15 >> 1)) * 64 + spA * 8;
  const int rdB = (wn * 32 + (l15 >> 1)) * 64 + spA * 8;

  auto COMPUTE = [&](int slot){
    const int so = slot * 4096;
    bf16x8 af[4], bq[4];
    #pragma unroll
    for (int mf = 0; mf < 4; ++mf)
      af[mf] = *(const bf16x8*)&lA[so + rdA + mf * 512];
    #pragma unroll
    for (int nf = 0; nf < 4; ++nf)
      bq[nf] = *(const bf16x8*)&lB[so + rdB + nf * 512];
    #pragma unroll
    for (int mf = 0; mf < 4; ++mf)
      #pragma unroll
      for (int nf = 0; nf < 4; ++nf)
        acc[mf][nf] = __builtin_amdgcn_mfma_f32_16x16x32_bf16(af[mf], bq[nf], acc[mf][nf], 0, 0, 0);
  };

  STAGE(0, 0); STAGE(1, 1); STAGE(2, 2); STAGE(3, 3);

  int sr = 0, sw = 4;
  for (int t = 0; t + 4 <= NT; ++t){
    asm volatile("s_waitcnt vmcnt(12)" ::: "memory");
    asm volatile("s_barrier" ::: "memory");
    if (t + 4 < NT){ STAGE(sw, t + 4); }
    COMPUTE(sr);
    sr = (sr == 4) ? 0 : sr + 1;
    sw = (sw == 4) ? 0 : sw + 1;
  }
  asm volatile("s_waitcnt vmcnt(8)" ::: "memory");
  asm volatile("s_barrier" ::: "memory");
  COMPUTE(sr); sr = (sr == 4) ? 0 : sr + 1;
  asm volatile("s_waitcnt vmcnt(4)" ::: "memory");
  asm volatile("s_barrier" ::: "memory");
  COMPUTE(sr); sr = (sr == 4) ? 0 : sr + 1;
  asm volatile("s_waitcnt vmcnt(0)" ::: "memory");
  asm volatile("s_barrier" ::: "memory");
  COMPUTE(sr);

  if (EPI == 0 || EPI == 1){
    #pragma unroll
    for (int mf = 0; mf < 4; ++mf){
      #pragma unroll
      for (int nf = 0; nf < 4; ++nf){
        int  n    = n0 + wn * 64 + nf * 16 + l15;
        long mrow = m0 + wm * 64 + mf * 16 + lk * 4;
        float bz = bias[n];
        #pragma unroll
        for (int r = 0; r < 4; ++r){
          float v = acc[mf][nf][r] + bz;
          long off = (mrow + r) * N + n;
          if (EPI == 0) v = gelu_exact(v) + resid[off];
          outb[off] = f2bf(v);
        }
      }
    }
  } else {
    const int a  = lane & 3;
    const int qb = lane & ~3;
    #pragma unroll
    for (int mf = 0; mf < 4; ++mf){
      #pragma unroll
      for (int nf = 0; nf < 4; ++nf){
        int n = n0 + wn * 64 + nf * 16 + l15;
        float bz = bias[n];
        float v0 = acc[mf][nf][0] + bz;
        float v1 = acc[mf][nf][1] + bz;
        float v2 = acc[mf][nf][2] + bz;
        float v3 = acc[mf][nf][3] + bz;
        float s0 = (a == 0) ? v0 : (a == 1) ? v1 : (a == 2) ? v2 : v3;
        float s1 = (a == 0) ? v1 : (a == 1) ? v2 : (a == 2) ? v3 : v0;
        float s2 = (a == 0) ? v2 : (a == 1) ? v3 : (a == 2) ? v0 : v1;
        float s3 = (a == 0) ? v3 : (a == 1) ? v0 : (a == 2) ? v1 : v2;
        float r0 = s0;
        float r1 = __shfl(s1, qb + ((a + 3) & 3));
        float r2 = __shfl(s2, qb + ((a + 2) & 3));
        float r3 = __shfl(s3, qb + ((a + 1) & 3));
        float wi = (a == 0) ? r0 : (a == 1) ? r1 : (a == 2) ? r2 : r3;
        float wf = (a == 1) ? r0 : (a == 2) ? r1 : (a == 3) ? r2 : r3;
        float wg = (a == 2) ? r0 : (a == 3) ? r1 : (a == 0) ? r2 : r3;
        float wo = (a == 3) ? r0 : (a == 0) ? r1 : (a == 1) ? r2 : r3;
        long row = m0 + wm * 64 + mf * 16 + lk * 4 + a;
        int  u   = ((n0 + wn * 64 + nf * 16) >> 2) + (l15 >> 2);
        float c_old = (tstep == 0) ? 0.0f : cbuf[row * 256 + u];
        float ii = fsig(wi), ff = fsig(wf), gg = ftanh(wg), oo = fsig(wo);
        float cn = ff * c_old + ii * gg;
        float hn = oo * ftanh(cn);
        cbuf[row * 256 + u] = cn;
        outb[(row * NVIEW + tstep) * 256 + u] = f2bf(hn);
      }
    }
  }
}

// ---------- tail: viewport + score + mean ----------
__global__ void k_score(const u16* __restrict__ X3, const float* __restrict__ Wv,
                        const float* __restrict__ bv, const float* __restrict__ Ws,
                        const float* __restrict__ bs, float* __restrict__ score){
  int lane = threadIdx.x & 63;
  int bm = blockIdx.x * 4 + (threadIdx.x >> 6);
  const u16* row = X3 + (long)bm * (NVIEW * 256);
  float4 wv = *(const float4*)(Wv + lane * 4);
  float p = 0.f;
  #pragma unroll
  for (int n = 0; n < NVIEW; ++n){
    ushort4 xv = *(const ushort4*)(row + n * 256 + lane * 4);
    float d = bf2f(xv.x) * wv.x + bf2f(xv.y) * wv.y + bf2f(xv.z) * wv.z + bf2f(xv.w) * wv.w;
    p += Ws[n] * d;
  }
  #pragma unroll
  for (int off = 32; off; off >>= 1) p += __shfl_xor(p, off);
  if (lane == 0){
    float sw = Ws[0] + Ws[1] + Ws[2] + Ws[3] + Ws[4] + Ws[5];
    score[bm] = p + bv[0] * sw + bs[0];
  }
}

__global__ void k_mean(const float* __restrict__ score, float* __restrict__ out){
  __shared__ float red[256];
  int b = blockIdx.x, tid = threadIdx.x;
  red[tid] = score[b * 256 + tid];
  __syncthreads();
  for (int s = 128; s > 0; s >>= 1){
    if (tid < s) red[tid] += red[tid + s];
    __syncthreads();
  }
  if (tid == 0) out[b] = red[0] * (1.0f / 256.0f);
}

// ---------- launcher ----------
extern "C" void kernel_launch(void* const* d_in, const int* in_sizes, int n_in,
                              void* d_out, int out_size, void* d_ws, size_t ws_size,
                              hipStream_t stream){
  const float* swin = (const float*)d_in[0];
  const float* conv = (const float*)d_in[1];
  const float* Wc   = (const float*)d_in[2];
  const float* bc   = (const float*)d_in[3];
  const float* Win  = (const float*)d_in[4];
  const float* b_in = (const float*)d_in[5];
  const float* Wih  = (const float*)d_in[6];
  const float* Whh  = (const float*)d_in[7];
  const float* bih  = (const float*)d_in[8];
  const float* bhh  = (const float*)d_in[9];
  const float* Wv   = (const float*)d_in[10];
  const float* bv   = (const float*)d_in[11];
  const float* Ws   = (const float*)d_in[12];
  const float* bs   = (const float*)d_in[13];
  float* out = (float*)d_out;

  char* w = (char*)d_ws;
  u16*  convb = (u16*)(w);
  u16*  X0    = (u16*)(w);
  u16*  XA    = (u16*)(w + 25165824);
  u16*  XB    = (u16*)(w + 50331648);
  float* cbuf = (float*)(w + 75497472);
  u16*  Y     = (u16*)(w + 100663296);
  u16*  Wcb   = (u16*)(w + 201326592);
  u16*  Winb  = (u16*)(w + 203423744);
  u16*  Wl    = (u16*)(w + 203948032);
  float* biasL= (float*)(w + 207093760);
  u16*  zbuf  = (u16*)(w + 207106048);
  float* scoreb = (float*)(w + 207106560);

  k_cvt<<<4096, 256, 0, stream>>>(conv, convb, 49152L * 1024 / 4);
  k_cvt<<<512, 256, 0, stream>>>(Wc, Wcb, 1048576 / 4);
  k_cvt<<<128, 256, 0, stream>>>(Win, Winb, 262144 / 4);
  k_build_wl<<<6144, 256, 0, stream>>>(Wih, Whh, Wl);
  k_build_bias<<<12, 256, 0, stream>>>(bih, bhh, biasL, zbuf);

  // G1 (8-phase read-ahead): Y = bf16( gelu(conv @ Wc^T + bc) + swin )  [49152x1024]
  gemm8<0><<<768, 512, 0, stream>>>(convb, 1024L, Wcb, 1024L,
                                    1024, 1024, 4, bc, swin, Y);

  // G2 (deep-ring): X0 = bf16( Y @ Win^T + b_in )   [49152 x 256], NBn=2
  gemm_dr<1><<<768, 256, 0, stream>>>(
      Y, 1024L, Y, 1024L, 1024,
      Winb, 1024L, 256, 1024, 2, b_in, (const float*)nullptr, X0, (float*)nullptr, 0);

  // LSTM: 3 layers x 6 timesteps
  const u16* xin = X0;
  u16* xout = XA;
  for (int l = 0; l < 3; ++l){
    for (int t = 0; t < 6; ++t){
      const u16* a1 = (t == 0) ? zbuf : (xout + (t - 1) * 256);
      long s1 = (t == 0) ? 0L : 1536L;
      gemm_dr<2><<<512, 256, 0, stream>>>(
          xin + t * 256, 1536L, a1, s1, 256,
          Wl + l * 1024 * 512, 512L, 1024, 512, 8,
          biasL + l * 1024, (const float*)nullptr,
          xout, cbuf, t);
    }
    if (l == 0){ xin = XA; xout = XB; }
    else if (l == 1){ xin = XB; xout = XA; }
  }

  k_score<<<2048, 256, 0, stream>>>(XA, Wv, bv, Ws, bs, scoreb);
  k_mean<<<32, 256, 0, stream>>>(scoreb, out);
}